// Round 5
// baseline (432.087 us; speedup 1.0000x reference)
//
#include <hip/hip_runtime.h>
#include <cstdint>

typedef __attribute__((ext_vector_type(8))) short short8;
typedef __attribute__((ext_vector_type(4))) float f32x4;

static constexpr int NN = 16384, FF = 256, GG = 64, EE = 131072, LL = 3;
static constexpr int HIDN = 512, IU = 32640, IN1 = 33408;
#define EPSV 1e-5f

__device__ inline unsigned short bf16r(float v) {
  unsigned u = __float_as_uint(v);
  u += 0x7FFFu + ((u >> 16) & 1u);
  return (unsigned short)(u >> 16);
}

// ---------------- deg histogram + cnt (LDS histogram) ----------------
__global__ __launch_bounds__(256) void k_hist(const int* __restrict__ dst,
                                              const int* __restrict__ batch,
                                              int* __restrict__ deg, int* __restrict__ cnt) {
  __shared__ int hist[64];
  int bx = blockIdx.x, t = threadIdx.x;
  if (bx < 512) {
    int e = bx * 256 + t;
    atomicAdd(&deg[dst[e]], 1);
  } else {
    if (t < 64) hist[t] = 0;
    __syncthreads();
    int4 v = ((const int4*)batch)[(bx - 512) * 256 + t];
    int a[4] = {v.x, v.y, v.z, v.w};
    int cur = a[0], run = 1;
#pragma unroll
    for (int j = 1; j < 4; ++j) {
      if (a[j] == cur) run++;
      else { atomicAdd(&hist[cur], run); cur = a[j]; run = 1; }
    }
    atomicAdd(&hist[cur], run);
    __syncthreads();
    if (t < 64 && hist[t]) atomicAdd(&cnt[t], hist[t]);
  }
}

// ---------------- conv layer via MFMA bf16-pair: C = deg*(A@W+b), fused pooling ------
// grid (2, 256): n0 = bx*128, m0 = by*64. 256 thr = 4 waves, wave w owns cols wn=w*32.
// Split-precision: v = hi + lo (two bf16); acc += Ahi*Bhi + Ahi*Blo + Alo*Bhi (~fp32).
// k-slot convention identical for A and B loads -> any HW k-permutation cancels.
__global__ __launch_bounds__(256, 2) void k_conv(const float* __restrict__ A,
                                                 const float* __restrict__ W,
                                                 const float* __restrict__ bias,
                                                 const int* __restrict__ deg,
                                                 float* __restrict__ C,
                                                 float* __restrict__ pooled, int lofs) {
  __shared__ __align__(16) unsigned short Ah[64][72], Al[64][72];
  __shared__ __align__(16) unsigned short Bh[128][72], Bl[128][72];
  int n0 = blockIdx.x * 128, m0 = blockIdx.y * 64;
  int t = threadIdx.x;
  int w = t >> 6, l = t & 63;
  int wn = w * 32;
  int lr = l & 15, lg = l >> 4;
  f32x4 acc[4][2];
#pragma unroll
  for (int fm = 0; fm < 4; ++fm)
#pragma unroll
    for (int fn = 0; fn < 2; ++fn) acc[fm][fn] = (f32x4){0.f, 0.f, 0.f, 0.f};

  int am = t >> 2, aq = t & 3;
  int bkp = t & 3, bnf = (t >> 2) & 31, brr = t >> 7;

  for (int ks = 0; ks < 4; ++ks) {
    int k0 = ks * 64;
    if (ks) __syncthreads();
    // ---- stage A tile (64 rows x 64 k), bank-tuned k-interleave ----
    {
      const float* ap = A + (size_t)(m0 + am) * FF + k0;
#pragma unroll
      for (int i = 0; i < 4; ++i) {
        int k = aq * 4 + i * 16;
        float4 v = *(const float4*)(ap + k);
        const float* vf = (const float*)&v;
        unsigned short h[4], lo[4];
#pragma unroll
        for (int j = 0; j < 4; ++j) {
          h[j] = bf16r(vf[j]);
          lo[j] = bf16r(vf[j] - __uint_as_float((unsigned)h[j] << 16));
        }
        *(uint2*)&Ah[am][k] = make_uint2((unsigned)h[0] | ((unsigned)h[1] << 16),
                                         (unsigned)h[2] | ((unsigned)h[3] << 16));
        *(uint2*)&Al[am][k] = make_uint2((unsigned)lo[0] | ((unsigned)lo[1] << 16),
                                         (unsigned)lo[2] | ((unsigned)lo[3] << 16));
      }
    }
    // ---- stage B tile (64 k x 128 n), transposed to [n][k], k-pairs packed u32 ----
#pragma unroll
    for (int r2 = 0; r2 < 4; ++r2) {
      int k = 2 * bkp + 8 * (brr * 4 + r2);
      const float* wp = W + (size_t)(k0 + k) * FF + n0 + bnf * 4;
      float4 va = *(const float4*)wp;
      float4 vb = *(const float4*)(wp + FF);
      const float* fa = (const float*)&va;
      const float* fb = (const float*)&vb;
#pragma unroll
      for (int j = 0; j < 4; ++j) {
        unsigned short ha = bf16r(fa[j]), hb = bf16r(fb[j]);
        unsigned short la = bf16r(fa[j] - __uint_as_float((unsigned)ha << 16));
        unsigned short lb = bf16r(fb[j] - __uint_as_float((unsigned)hb << 16));
        int n = bnf * 4 + j;
        *(unsigned*)&Bh[n][k] = (unsigned)ha | ((unsigned)hb << 16);
        *(unsigned*)&Bl[n][k] = (unsigned)la | ((unsigned)lb << 16);
      }
    }
    __syncthreads();
    // ---- compute: 2 K-steps of 32 ----
#pragma unroll
    for (int k2 = 0; k2 < 2; ++k2) {
      int kk = k2 * 32 + lg * 8;
      short8 afh[4], afl[4], bfh[2], bfl[2];
#pragma unroll
      for (int fm = 0; fm < 4; ++fm) {
        afh[fm] = *(const short8*)&Ah[fm * 16 + lr][kk];
        afl[fm] = *(const short8*)&Al[fm * 16 + lr][kk];
      }
#pragma unroll
      for (int fn = 0; fn < 2; ++fn) {
        bfh[fn] = *(const short8*)&Bh[wn + fn * 16 + lr][kk];
        bfl[fn] = *(const short8*)&Bl[wn + fn * 16 + lr][kk];
      }
#pragma unroll
      for (int fm = 0; fm < 4; ++fm)
#pragma unroll
        for (int fn = 0; fn < 2; ++fn) {
          acc[fm][fn] = __builtin_amdgcn_mfma_f32_16x16x32_bf16(afl[fm], bfh[fn], acc[fm][fn], 0, 0, 0);
          acc[fm][fn] = __builtin_amdgcn_mfma_f32_16x16x32_bf16(afh[fm], bfl[fn], acc[fm][fn], 0, 0, 0);
          acc[fm][fn] = __builtin_amdgcn_mfma_f32_16x16x32_bf16(afh[fm], bfh[fn], acc[fm][fn], 0, 0, 0);
        }
    }
  }
  // ---- epilogue: bias + deg scale + store + fused column-sum pooling ----
  float degf[4][4];
#pragma unroll
  for (int fm = 0; fm < 4; ++fm)
#pragma unroll
    for (int r = 0; r < 4; ++r)
      degf[fm][r] = (float)(deg[m0 + fm * 16 + lg * 4 + r] + 1);  // +1 self loop
  int g = m0 >> 8;
#pragma unroll
  for (int fn = 0; fn < 2; ++fn) {
    int col = n0 + wn + fn * 16 + lr;
    float bb = bias[col];
    float cs = 0.f;
#pragma unroll
    for (int fm = 0; fm < 4; ++fm) {
      const float* av = (const float*)&acc[fm][fn];
#pragma unroll
      for (int r = 0; r < 4; ++r) {
        int row = m0 + fm * 16 + lg * 4 + r;
        float v = (av[r] + bb) * degf[fm][r];
        C[(size_t)row * FF + col] = v;
        cs += v;
      }
    }
    cs += __shfl_xor(cs, 16);
    cs += __shfl_xor(cs, 32);
    if (lg == 0) atomicAdd(&pooled[(size_t)g * (FF * LL) + lofs + col], cs);
  }
}

// ---------------- front BN: xt (blocks 0..255) + pooled (blocks 256..258) -> z ----------------
__global__ __launch_bounds__(256) void k_bn_front(const float* __restrict__ x,
                                                  const float* __restrict__ bn_g,
                                                  const float* __restrict__ bn_b,
                                                  const float* __restrict__ pooled,
                                                  const int* __restrict__ cnt,
                                                  const float* __restrict__ bnh_g,
                                                  const float* __restrict__ bnh_b,
                                                  float* __restrict__ z) {
  int bx = blockIdx.x;
  if (bx < 256) {
    int i = bx, j = threadIdx.x;
    if (j <= i) return;
    int p = i * 255 - (i * (i - 1)) / 2 + (j - i - 1);
    float vals[64];
    float s = 0.f, s2 = 0.f;
#pragma unroll
    for (int g = 0; g < 64; ++g) {
      float v = x[(size_t)(g * 256 + i) * FF + j];
      vals[g] = v;
      s += v;
      s2 += v * v;
    }
    float m = s * (1.f / 64.f);
    float var = s2 * (1.f / 64.f) - m * m;
    float rs = rsqrtf(var + EPSV) * bn_g[p];
    float bb = bn_b[p];
#pragma unroll
    for (int g = 0; g < 64; ++g) z[(size_t)g * IN1 + p] = (vals[g] - m) * rs + bb;
  } else {
    int q = (bx - 256) * 256 + threadIdx.x;
    if (q >= FF * LL) return;
    float vals[64];
    float s = 0.f, s2 = 0.f;
#pragma unroll
    for (int g = 0; g < 64; ++g) {
      float v = pooled[(size_t)g * (FF * LL) + q] / (float)cnt[g];
      vals[g] = v;
      s += v;
      s2 += v * v;
    }
    float m = s * (1.f / 64.f);
    float var = s2 * (1.f / 64.f) - m * m;
    float rs = rsqrtf(var + EPSV) * bnh_g[q];
    float bb = bnh_b[q];
#pragma unroll
    for (int g = 0; g < 64; ++g) z[(size_t)g * IN1 + IU + q] = (vals[g] - m) * rs + bb;
  }
}

// ---------------- w1 GEMM: partial[s][g][h], depth-8 prefetch ring ----------------
__global__ __launch_bounds__(256) void k_w1(const float* __restrict__ Z,
                                            const float* __restrict__ W,
                                            float* __restrict__ partial) {
  __shared__ float zl[64][132];
  int n0 = blockIdx.x * 64;
  int s = blockIdx.y;
  int tid = threadIdx.x;
  int hq = tid & 15, gq = tid >> 4;
  float acc[4][4] = {};
  for (int c = s; c < 261; c += 128) {  // 33408 = 261*128 exactly
    int p0 = c << 7;
#pragma unroll
    for (int it = 0; it < 8; ++it) {
      int idx = it * 256 + tid;
      int g = idx >> 5, kq = idx & 31;
      *(float4*)&zl[g][kq * 4] = *(const float4*)(Z + (size_t)g * IN1 + p0 + kq * 4);
    }
    __syncthreads();
    const float* wp = W + (size_t)p0 * HIDN + n0 + hq * 4;
    float4 wr[8];
#pragma unroll
    for (int j = 0; j < 8; ++j) wr[j] = *(const float4*)(wp + (size_t)j * HIDN);
    for (int kb = 0; kb < 128; kb += 8) {
#pragma unroll
      for (int j = 0; j < 8; ++j) {
        float4 wv = wr[j];
        int kn = kb + 8 + j;
        kn = kn < 128 ? kn : 127;
        wr[j] = *(const float4*)(wp + (size_t)kn * HIDN);
        int kk = kb + j;
        float zv[4];
#pragma unroll
        for (int i = 0; i < 4; ++i) zv[i] = zl[gq * 4 + i][kk];
#pragma unroll
        for (int i = 0; i < 4; ++i) {
          acc[i][0] = fmaf(zv[i], wv.x, acc[i][0]);
          acc[i][1] = fmaf(zv[i], wv.y, acc[i][1]);
          acc[i][2] = fmaf(zv[i], wv.z, acc[i][2]);
          acc[i][3] = fmaf(zv[i], wv.w, acc[i][3]);
        }
      }
    }
    __syncthreads();
  }
#pragma unroll
  for (int i = 0; i < 4; ++i) {
    int g = gq * 4 + i;
    *(float4*)(partial + ((size_t)s * 64 + g) * HIDN + n0 + hq * 4) = *(float4*)&acc[i][0];
  }
}

// ---------------- reduce K-splits + bias ----------------
__global__ __launch_bounds__(256) void k_reduce(const float* __restrict__ partial,
                                                const float* __restrict__ bias,
                                                float* __restrict__ out, int S, int N) {
  int idx = blockIdx.x * 256 + threadIdx.x;
  if (idx >= 64 * N) return;
  int h = idx % N;
  float a = bias[h];
  for (int s = 0; s < S; ++s) a += partial[(size_t)s * 64 * N + idx];
  out[idx] = a;
}

// ---------------- column-wise BN over 64 rows + ReLU ----------------
__global__ __launch_bounds__(64) void k_bn_relu(const float* __restrict__ in,
                                                const float* __restrict__ gamma,
                                                const float* __restrict__ beta,
                                                float* __restrict__ out, int N) {
  int h = blockIdx.x;
  int g = threadIdx.x;
  float v = in[(size_t)g * N + h];
  float s = v, s2 = v * v;
#pragma unroll
  for (int o = 32; o > 0; o >>= 1) {
    s += __shfl_xor(s, o);
    s2 += __shfl_xor(s2, o);
  }
  float m = s * (1.f / 64.f);
  float var = s2 * (1.f / 64.f) - m * m;
  float r = (v - m) * rsqrtf(var + EPSV) * gamma[h] + beta[h];
  out[(size_t)g * N + h] = fmaxf(r, 0.f);
}

// ---------------- fused small MLP layer: out = relu(BN(Z@W + b)), M=64 ----------------
__global__ __launch_bounds__(512) void k_mlp_small(const float* __restrict__ Z,
                                                   const float* __restrict__ W,
                                                   const float* __restrict__ bias,
                                                   const float* __restrict__ gamma,
                                                   const float* __restrict__ beta,
                                                   float* __restrict__ out, int K, int N) {
  __shared__ float zl[64][132];
  __shared__ float sb1[8][72], sb2[8][72];
  int t = threadIdx.x;
  int hl = t & 63, gq = t >> 6;
  int h0 = blockIdx.x * 64;
  float acc[8] = {};
  for (int c = 0; c < K; c += 128) {
#pragma unroll
    for (int it = 0; it < 4; ++it) {
      int idx = it * 512 + t;
      int g = idx >> 5, kq = idx & 31;
      *(float4*)&zl[g][kq * 4] = *(const float4*)(Z + (size_t)g * K + c + kq * 4);
    }
    __syncthreads();
    for (int kk = 0; kk < 128; ++kk) {
      float w = W[(size_t)(c + kk) * N + h0 + hl];
#pragma unroll
      for (int i = 0; i < 8; ++i) acc[i] = fmaf(zl[gq * 8 + i][kk], w, acc[i]);
    }
    __syncthreads();
  }
  float bb = bias[h0 + hl];
  float s1 = 0.f, s2 = 0.f;
#pragma unroll
  for (int i = 0; i < 8; ++i) {
    acc[i] += bb;
    s1 += acc[i];
    s2 += acc[i] * acc[i];
  }
  sb1[gq][hl] = s1;
  sb2[gq][hl] = s2;
  __syncthreads();
  float S1 = 0.f, S2 = 0.f;
#pragma unroll
  for (int q = 0; q < 8; ++q) { S1 += sb1[q][hl]; S2 += sb2[q][hl]; }
  float m = S1 * (1.f / 64.f);
  float var = S2 * (1.f / 64.f) - m * m;
  float rs = rsqrtf(var + EPSV) * gamma[h0 + hl];
  float be = beta[h0 + hl];
#pragma unroll
  for (int i = 0; i < 8; ++i)
    out[(size_t)(gq * 8 + i) * N + h0 + hl] = fmaxf((acc[i] - m) * rs + be, 0.f);
}

// ---------------- final: out = A @ w4 + b4, [64,256]@[256,2], wave-parallel ----------------
__global__ __launch_bounds__(256) void k_final(const float* __restrict__ A,
                                               const float* __restrict__ w4,
                                               const float* __restrict__ b4,
                                               float* __restrict__ out) {
  __shared__ float w4l[512];
  int t = threadIdx.x;
  w4l[t] = w4[t];
  w4l[256 + t] = w4[256 + t];
  __syncthreads();
  int w = t >> 6, l = t & 63;
  for (int g = w * 16; g < w * 16 + 16; ++g) {
    float4 av = *(const float4*)(A + (size_t)g * 256 + l * 4);
    float c0 = av.x * w4l[(l * 4 + 0) * 2] + av.y * w4l[(l * 4 + 1) * 2] +
               av.z * w4l[(l * 4 + 2) * 2] + av.w * w4l[(l * 4 + 3) * 2];
    float c1 = av.x * w4l[(l * 4 + 0) * 2 + 1] + av.y * w4l[(l * 4 + 1) * 2 + 1] +
               av.z * w4l[(l * 4 + 2) * 2 + 1] + av.w * w4l[(l * 4 + 3) * 2 + 1];
#pragma unroll
    for (int o = 32; o > 0; o >>= 1) {
      c0 += __shfl_xor(c0, o);
      c1 += __shfl_xor(c1, o);
    }
    if (l == 0) {
      out[g * 2 + 0] = c0 + b4[0];
      out[g * 2 + 1] = c1 + b4[1];
    }
  }
}

extern "C" void kernel_launch(void* const* d_in, const int* in_sizes, int n_in,
                              void* d_out, int out_size, void* d_ws, size_t ws_size,
                              hipStream_t stream) {
  const float* x = (const float*)d_in[0];
  const int* edge = (const int*)d_in[1];
  const int* batch = (const int*)d_in[2];
  // d_in[3],[4] lin_src_w/b: dead. d_in[7],[8] att_w/b: dead (softmax over singleton = 1).
  const float* lin_dst_w = (const float*)d_in[5];
  const float* lin_dst_b = (const float*)d_in[6];
  const float* bn_g = (const float*)d_in[9];
  const float* bn_b = (const float*)d_in[10];
  const float* bnh_g = (const float*)d_in[11];
  const float* bnh_b = (const float*)d_in[12];
  const float* w1 = (const float*)d_in[13];
  const float* b1 = (const float*)d_in[14];
  const float* g1 = (const float*)d_in[15];
  const float* be1 = (const float*)d_in[16];
  const float* w2 = (const float*)d_in[17];
  const float* b2 = (const float*)d_in[18];
  const float* g2 = (const float*)d_in[19];
  const float* be2 = (const float*)d_in[20];
  const float* w3 = (const float*)d_in[21];
  const float* b3 = (const float*)d_in[22];
  const float* g3 = (const float*)d_in[23];
  const float* be3 = (const float*)d_in[24];
  const float* w4 = (const float*)d_in[25];
  const float* b4 = (const float*)d_in[26];
  const int* dstp = edge + EE;  // edge_index[1]

  char* ws = (char*)d_ws;
  int* deg = (int*)(ws);                                     // 64 KB
  int* cnt = (int*)(ws + 65536);                             // 256 B
  float* bufA = (float*)(ws + 131072);                       // 16 MiB
  float* bufB = (float*)(ws + 131072 + 16777216);            // 16 MiB
  float* pooled = (float*)(ws + 131072 + 2 * 16777216);      // 192 KB
  char* tail = ws + 131072 + 2 * 16777216 + 196608;
  float* m1 = (float*)(tail);                                // 64x512
  float* m1b = (float*)(tail + 131072);
  float* m2b = (float*)(tail + 262144);                      // 64x256
  float* m3b = (float*)(tail + 262144 + 65536);
  float* z = bufA;       // reused after layer-3 conv (h3 dead once pooled)
  float* partial = bufB; // S=128: 128*64*512*4 = 16,777,216 B == bufB exactly

  hipMemsetAsync(ws, 0, 131072, stream);            // deg + cnt
  hipMemsetAsync(pooled, 0, 196608, stream);        // pooled accumulators

  k_hist<<<528, 256, 0, stream>>>(dstp, batch, deg, cnt);

  // ---- 3 conv layers (MFMA bf16-pair), pooling fused into epilogue ----
  const float* hin = x;
  float* houts[3] = {bufA, bufB, bufA};
  for (int l = 0; l < LL; ++l) {
    k_conv<<<dim3(2, 256), 256, 0, stream>>>(hin, lin_dst_w + (size_t)l * FF * FF,
                                             lin_dst_b + (size_t)l * FF, deg, houts[l],
                                             pooled, l * FF);
    hin = houts[l];
  }

  // ---- build z = [BN(xt) | BN(pooled/cnt)] ----
  k_bn_front<<<259, 256, 0, stream>>>(x, bn_g, bn_b, pooled, cnt, bnh_g, bnh_b, z);

  // ---- MLP ----
  k_w1<<<dim3(8, 128), 256, 0, stream>>>(z, w1, partial);
  k_reduce<<<128, 256, 0, stream>>>(partial, b1, m1, 128, HIDN);
  k_bn_relu<<<HIDN, 64, 0, stream>>>(m1, g1, be1, m1b, HIDN);

  k_mlp_small<<<4, 512, 0, stream>>>(m1b, w2, b2, g2, be2, m2b, HIDN, 256);
  k_mlp_small<<<4, 512, 0, stream>>>(m2b, w3, b3, g3, be3, m3b, 256, 256);

  k_final<<<1, 256, 0, stream>>>(m3b, w4, b4, (float*)d_out);
}

// Round 6
// 226.005 us; speedup vs baseline: 1.9119x; 1.9119x over previous
//
#include <hip/hip_runtime.h>
#include <cstdint>

typedef __attribute__((ext_vector_type(8))) short short8;
typedef __attribute__((ext_vector_type(4))) float f32x4;
typedef unsigned short ushort_t;

static constexpr int NN = 16384, FF = 256, GG = 64, EE = 131072, LL = 3;
static constexpr int HIDN = 512, IU = 32640, IN1 = 33408;
#define EPSV 1e-5f

__device__ inline unsigned short bf16r(float v) {
  unsigned u = __float_as_uint(v);
  u += 0x7FFFu + ((u >> 16) & 1u);
  return (unsigned short)(u >> 16);
}

// ---------------- deg histogram + cnt (LDS histogram) ----------------
__global__ __launch_bounds__(256) void k_hist(const int* __restrict__ dst,
                                              const int* __restrict__ batch,
                                              int* __restrict__ deg, int* __restrict__ cnt) {
  __shared__ int hist[64];
  int bx = blockIdx.x, t = threadIdx.x;
  if (bx < 512) {
    int e = bx * 256 + t;
    atomicAdd(&deg[dst[e]], 1);
  } else {
    if (t < 64) hist[t] = 0;
    __syncthreads();
    int4 v = ((const int4*)batch)[(bx - 512) * 256 + t];
    int a[4] = {v.x, v.y, v.z, v.w};
    int cur = a[0], run = 1;
#pragma unroll
    for (int j = 1; j < 4; ++j) {
      if (a[j] == cur) run++;
      else { atomicAdd(&hist[cur], run); cur = a[j]; run = 1; }
    }
    atomicAdd(&hist[cur], run);
    __syncthreads();
    if (t < 64 && hist[t]) atomicAdd(&cnt[t], hist[t]);
  }
}

// ---------------- conv layer via MFMA bf16-pair: C = deg*(A@W+b), fused pooling ------
__global__ __launch_bounds__(256, 2) void k_conv(const float* __restrict__ A,
                                                 const float* __restrict__ W,
                                                 const float* __restrict__ bias,
                                                 const int* __restrict__ deg,
                                                 float* __restrict__ C,
                                                 float* __restrict__ pooled, int lofs) {
  __shared__ __align__(16) unsigned short Ah[64][72], Al[64][72];
  __shared__ __align__(16) unsigned short Bh[128][72], Bl[128][72];
  int n0 = blockIdx.x * 128, m0 = blockIdx.y * 64;
  int t = threadIdx.x;
  int w = t >> 6, l = t & 63;
  int wn = w * 32;
  int lr = l & 15, lg = l >> 4;
  f32x4 acc[4][2];
#pragma unroll
  for (int fm = 0; fm < 4; ++fm)
#pragma unroll
    for (int fn = 0; fn < 2; ++fn) acc[fm][fn] = (f32x4){0.f, 0.f, 0.f, 0.f};

  int am = t >> 2, aq = t & 3;
  int bkp = t & 3, bnf = (t >> 2) & 31, brr = t >> 7;

  for (int ks = 0; ks < 4; ++ks) {
    int k0 = ks * 64;
    if (ks) __syncthreads();
    {
      const float* ap = A + (size_t)(m0 + am) * FF + k0;
#pragma unroll
      for (int i = 0; i < 4; ++i) {
        int k = aq * 4 + i * 16;
        float4 v = *(const float4*)(ap + k);
        const float* vf = (const float*)&v;
        unsigned short h[4], lo[4];
#pragma unroll
        for (int j = 0; j < 4; ++j) {
          h[j] = bf16r(vf[j]);
          lo[j] = bf16r(vf[j] - __uint_as_float((unsigned)h[j] << 16));
        }
        *(uint2*)&Ah[am][k] = make_uint2((unsigned)h[0] | ((unsigned)h[1] << 16),
                                         (unsigned)h[2] | ((unsigned)h[3] << 16));
        *(uint2*)&Al[am][k] = make_uint2((unsigned)lo[0] | ((unsigned)lo[1] << 16),
                                         (unsigned)lo[2] | ((unsigned)lo[3] << 16));
      }
    }
#pragma unroll
    for (int r2 = 0; r2 < 4; ++r2) {
      int k = 2 * bkp + 8 * (brr * 4 + r2);
      const float* wp = W + (size_t)(k0 + k) * FF + n0 + bnf * 4;
      float4 va = *(const float4*)wp;
      float4 vb = *(const float4*)(wp + FF);
      const float* fa = (const float*)&va;
      const float* fb = (const float*)&vb;
#pragma unroll
      for (int j = 0; j < 4; ++j) {
        unsigned short ha = bf16r(fa[j]), hb = bf16r(fb[j]);
        unsigned short la = bf16r(fa[j] - __uint_as_float((unsigned)ha << 16));
        unsigned short lb = bf16r(fb[j] - __uint_as_float((unsigned)hb << 16));
        int n = bnf * 4 + j;
        *(unsigned*)&Bh[n][k] = (unsigned)ha | ((unsigned)hb << 16);
        *(unsigned*)&Bl[n][k] = (unsigned)la | ((unsigned)lb << 16);
      }
    }
    __syncthreads();
#pragma unroll
    for (int k2 = 0; k2 < 2; ++k2) {
      int kk = k2 * 32 + lg * 8;
      short8 afh[4], afl[4], bfh[2], bfl[2];
#pragma unroll
      for (int fm = 0; fm < 4; ++fm) {
        afh[fm] = *(const short8*)&Ah[fm * 16 + lr][kk];
        afl[fm] = *(const short8*)&Al[fm * 16 + lr][kk];
      }
#pragma unroll
      for (int fn = 0; fn < 2; ++fn) {
        bfh[fn] = *(const short8*)&Bh[wn + fn * 16 + lr][kk];
        bfl[fn] = *(const short8*)&Bl[wn + fn * 16 + lr][kk];
      }
#pragma unroll
      for (int fm = 0; fm < 4; ++fm)
#pragma unroll
        for (int fn = 0; fn < 2; ++fn) {
          acc[fm][fn] = __builtin_amdgcn_mfma_f32_16x16x32_bf16(afl[fm], bfh[fn], acc[fm][fn], 0, 0, 0);
          acc[fm][fn] = __builtin_amdgcn_mfma_f32_16x16x32_bf16(afh[fm], bfl[fn], acc[fm][fn], 0, 0, 0);
          acc[fm][fn] = __builtin_amdgcn_mfma_f32_16x16x32_bf16(afh[fm], bfh[fn], acc[fm][fn], 0, 0, 0);
        }
    }
  }
  float degf[4][4];
#pragma unroll
  for (int fm = 0; fm < 4; ++fm)
#pragma unroll
    for (int r = 0; r < 4; ++r)
      degf[fm][r] = (float)(deg[m0 + fm * 16 + lg * 4 + r] + 1);  // +1 self loop
  int g = m0 >> 8;
#pragma unroll
  for (int fn = 0; fn < 2; ++fn) {
    int col = n0 + wn + fn * 16 + lr;
    float bb = bias[col];
    float cs = 0.f;
#pragma unroll
    for (int fm = 0; fm < 4; ++fm) {
      const float* av = (const float*)&acc[fm][fn];
#pragma unroll
      for (int r = 0; r < 4; ++r) {
        int row = m0 + fm * 16 + lg * 4 + r;
        float v = (av[r] + bb) * degf[fm][r];
        if (C) C[(size_t)row * FF + col] = v;
        cs += v;
      }
    }
    cs += __shfl_xor(cs, 16);
    cs += __shfl_xor(cs, 32);
    if (lg == 0) atomicAdd(&pooled[(size_t)g * (FF * LL) + lofs + col], cs);
  }
}

// ---------------- front BN -> z emitted as bf16 hi/lo pair ----------------
__global__ __launch_bounds__(256) void k_bn_front(const float* __restrict__ x,
                                                  const float* __restrict__ bn_g,
                                                  const float* __restrict__ bn_b,
                                                  const float* __restrict__ pooled,
                                                  const int* __restrict__ cnt,
                                                  const float* __restrict__ bnh_g,
                                                  const float* __restrict__ bnh_b,
                                                  ushort_t* __restrict__ zh,
                                                  ushort_t* __restrict__ zl) {
  int bx = blockIdx.x;
  if (bx < 256) {
    int i = bx, j = threadIdx.x;
    if (j <= i) return;
    int p = i * 255 - (i * (i - 1)) / 2 + (j - i - 1);
    float vals[64];
    float s = 0.f, s2 = 0.f;
#pragma unroll
    for (int g = 0; g < 64; ++g) {
      float v = x[(size_t)(g * 256 + i) * FF + j];
      vals[g] = v;
      s += v;
      s2 += v * v;
    }
    float m = s * (1.f / 64.f);
    float var = s2 * (1.f / 64.f) - m * m;
    float rs = rsqrtf(var + EPSV) * bn_g[p];
    float bb = bn_b[p];
#pragma unroll
    for (int g = 0; g < 64; ++g) {
      float v = (vals[g] - m) * rs + bb;
      unsigned short h = bf16r(v);
      unsigned short lo = bf16r(v - __uint_as_float((unsigned)h << 16));
      zh[(size_t)g * IN1 + p] = h;
      zl[(size_t)g * IN1 + p] = lo;
    }
  } else {
    int q = (bx - 256) * 256 + threadIdx.x;
    if (q >= FF * LL) return;
    float vals[64];
    float s = 0.f, s2 = 0.f;
#pragma unroll
    for (int g = 0; g < 64; ++g) {
      float v = pooled[(size_t)g * (FF * LL) + q] / (float)cnt[g];
      vals[g] = v;
      s += v;
      s2 += v * v;
    }
    float m = s * (1.f / 64.f);
    float var = s2 * (1.f / 64.f) - m * m;
    float rs = rsqrtf(var + EPSV) * bnh_g[q];
    float bb = bnh_b[q];
#pragma unroll
    for (int g = 0; g < 64; ++g) {
      float v = (vals[g] - m) * rs + bb;
      unsigned short h = bf16r(v);
      unsigned short lo = bf16r(v - __uint_as_float((unsigned)h << 16));
      zh[(size_t)g * IN1 + IU + q] = h;
      zl[(size_t)g * IN1 + IU + q] = lo;
    }
  }
}

// ---------------- w1 GEMM via MFMA: partial[s][g][h], [64,33408]@[33408,512] ----------
// grid (8 nb, 128 s), 256 thr = 4 waves; wave w -> cols nb*64+w*16+lr.
// A = z (bf16 pairs, LDS-staged); B = W fp32 loaded per-lane in fragment pattern,
// split hi/lo in-register (trunc-hi + round-lo). 3 MFMAs per tile (drop lo*lo).
__global__ __launch_bounds__(256, 2) void k_w1(const ushort_t* __restrict__ zh,
                                               const ushort_t* __restrict__ zl,
                                               const float* __restrict__ W,
                                               float* __restrict__ partial) {
  __shared__ __align__(16) unsigned short Zh[64][136], Zl[64][136];
  int nb = blockIdx.x, s = blockIdx.y;
  int t = threadIdx.x;
  int w = t >> 6, l = t & 63, lr = l & 15, lg = l >> 4;
  int ncol = nb * 64 + w * 16 + lr;
  f32x4 acc[4];
#pragma unroll
  for (int mt = 0; mt < 4; ++mt) acc[mt] = (f32x4){0.f, 0.f, 0.f, 0.f};

  for (int c = s; c < 261; c += 128) {  // 33408 = 261*128
    int p0 = c << 7;
#pragma unroll
    for (int it = 0; it < 4; ++it) {
      int idx = it * 256 + t;
      int g = idx >> 4, kq = idx & 15;
      *(uint4*)&Zh[g][kq * 8] = *(const uint4*)(zh + (size_t)g * IN1 + p0 + kq * 8);
      *(uint4*)&Zl[g][kq * 8] = *(const uint4*)(zl + (size_t)g * IN1 + p0 + kq * 8);
    }
    __syncthreads();
#pragma unroll
    for (int k2 = 0; k2 < 4; ++k2) {
      int kloc = k2 * 32 + lg * 8;
      size_t kg = (size_t)(p0 + kloc);
      float wv[8];
#pragma unroll
      for (int j = 0; j < 8; ++j) wv[j] = W[(kg + j) * HIDN + ncol];
      short8 bh, bl;
#pragma unroll
      for (int j = 0; j < 8; ++j) {
        unsigned u = __float_as_uint(wv[j]);
        unsigned hi = u & 0xFFFF0000u;
        float lo = wv[j] - __uint_as_float(hi);
        bh[j] = (short)(hi >> 16);
        bl[j] = (short)bf16r(lo);
      }
#pragma unroll
      for (int mt = 0; mt < 4; ++mt) {
        short8 ah = *(const short8*)&Zh[mt * 16 + lr][kloc];
        short8 al = *(const short8*)&Zl[mt * 16 + lr][kloc];
        acc[mt] = __builtin_amdgcn_mfma_f32_16x16x32_bf16(al, bh, acc[mt], 0, 0, 0);
        acc[mt] = __builtin_amdgcn_mfma_f32_16x16x32_bf16(ah, bl, acc[mt], 0, 0, 0);
        acc[mt] = __builtin_amdgcn_mfma_f32_16x16x32_bf16(ah, bh, acc[mt], 0, 0, 0);
      }
    }
    __syncthreads();
  }
#pragma unroll
  for (int mt = 0; mt < 4; ++mt) {
    const float* av = (const float*)&acc[mt];
#pragma unroll
    for (int r = 0; r < 4; ++r) {
      int g = mt * 16 + lg * 4 + r;
      partial[((size_t)s * 64 + g) * HIDN + ncol] = av[r];
    }
  }
}

// ---------------- reduce K-splits + bias ----------------
__global__ __launch_bounds__(256) void k_reduce(const float* __restrict__ partial,
                                                const float* __restrict__ bias,
                                                float* __restrict__ out, int S, int N) {
  int idx = blockIdx.x * 256 + threadIdx.x;
  if (idx >= 64 * N) return;
  int h = idx % N;
  float a = bias[h];
  for (int s = 0; s < S; ++s) a += partial[(size_t)s * 64 * N + idx];
  out[idx] = a;
}

// ---------------- column-wise BN over 64 rows + ReLU ----------------
__global__ __launch_bounds__(64) void k_bn_relu(const float* __restrict__ in,
                                                const float* __restrict__ gamma,
                                                const float* __restrict__ beta,
                                                float* __restrict__ out, int N) {
  int h = blockIdx.x;
  int g = threadIdx.x;
  float v = in[(size_t)g * N + h];
  float s = v, s2 = v * v;
#pragma unroll
  for (int o = 32; o > 0; o >>= 1) {
    s += __shfl_xor(s, o);
    s2 += __shfl_xor(s2, o);
  }
  float m = s * (1.f / 64.f);
  float var = s2 * (1.f / 64.f) - m * m;
  float r = (v - m) * rsqrtf(var + EPSV) * gamma[h] + beta[h];
  out[(size_t)g * N + h] = fmaxf(r, 0.f);
}

// ---------------- fused small MLP layer: out = relu(BN(Z@W + b)), M=64 ----------------
__global__ __launch_bounds__(512) void k_mlp_small(const float* __restrict__ Z,
                                                   const float* __restrict__ W,
                                                   const float* __restrict__ bias,
                                                   const float* __restrict__ gamma,
                                                   const float* __restrict__ beta,
                                                   float* __restrict__ out, int K, int N) {
  __shared__ float zl[64][132];
  __shared__ float sb1[8][72], sb2[8][72];
  int t = threadIdx.x;
  int hl = t & 63, gq = t >> 6;
  int h0 = blockIdx.x * 64;
  float acc[8] = {};
  for (int c = 0; c < K; c += 128) {
#pragma unroll
    for (int it = 0; it < 4; ++it) {
      int idx = it * 512 + t;
      int g = idx >> 5, kq = idx & 31;
      *(float4*)&zl[g][kq * 4] = *(const float4*)(Z + (size_t)g * K + c + kq * 4);
    }
    __syncthreads();
    for (int kk = 0; kk < 128; ++kk) {
      float w = W[(size_t)(c + kk) * N + h0 + hl];
#pragma unroll
      for (int i = 0; i < 8; ++i) acc[i] = fmaf(zl[gq * 8 + i][kk], w, acc[i]);
    }
    __syncthreads();
  }
  float bb = bias[h0 + hl];
  float s1 = 0.f, s2 = 0.f;
#pragma unroll
  for (int i = 0; i < 8; ++i) {
    acc[i] += bb;
    s1 += acc[i];
    s2 += acc[i] * acc[i];
  }
  sb1[gq][hl] = s1;
  sb2[gq][hl] = s2;
  __syncthreads();
  float S1 = 0.f, S2 = 0.f;
#pragma unroll
  for (int q = 0; q < 8; ++q) { S1 += sb1[q][hl]; S2 += sb2[q][hl]; }
  float m = S1 * (1.f / 64.f);
  float var = S2 * (1.f / 64.f) - m * m;
  float rs = rsqrtf(var + EPSV) * gamma[h0 + hl];
  float be = beta[h0 + hl];
#pragma unroll
  for (int i = 0; i < 8; ++i)
    out[(size_t)(gq * 8 + i) * N + h0 + hl] = fmaxf((acc[i] - m) * rs + be, 0.f);
}

// ---------------- final: out = A @ w4 + b4, [64,256]@[256,2], wave-parallel ----------------
__global__ __launch_bounds__(256) void k_final(const float* __restrict__ A,
                                               const float* __restrict__ w4,
                                               const float* __restrict__ b4,
                                               float* __restrict__ out) {
  __shared__ float w4l[512];
  int t = threadIdx.x;
  w4l[t] = w4[t];
  w4l[256 + t] = w4[256 + t];
  __syncthreads();
  int w = t >> 6, l = t & 63;
  for (int g = w * 16; g < w * 16 + 16; ++g) {
    float4 av = *(const float4*)(A + (size_t)g * 256 + l * 4);
    float c0 = av.x * w4l[(l * 4 + 0) * 2] + av.y * w4l[(l * 4 + 1) * 2] +
               av.z * w4l[(l * 4 + 2) * 2] + av.w * w4l[(l * 4 + 3) * 2];
    float c1 = av.x * w4l[(l * 4 + 0) * 2 + 1] + av.y * w4l[(l * 4 + 1) * 2 + 1] +
               av.z * w4l[(l * 4 + 2) * 2 + 1] + av.w * w4l[(l * 4 + 3) * 2 + 1];
#pragma unroll
    for (int o = 32; o > 0; o >>= 1) {
      c0 += __shfl_xor(c0, o);
      c1 += __shfl_xor(c1, o);
    }
    if (l == 0) {
      out[g * 2 + 0] = c0 + b4[0];
      out[g * 2 + 1] = c1 + b4[1];
    }
  }
}

extern "C" void kernel_launch(void* const* d_in, const int* in_sizes, int n_in,
                              void* d_out, int out_size, void* d_ws, size_t ws_size,
                              hipStream_t stream) {
  const float* x = (const float*)d_in[0];
  const int* edge = (const int*)d_in[1];
  const int* batch = (const int*)d_in[2];
  // d_in[3],[4] lin_src_w/b: dead. d_in[7],[8] att_w/b: dead (softmax over singleton = 1).
  const float* lin_dst_w = (const float*)d_in[5];
  const float* lin_dst_b = (const float*)d_in[6];
  const float* bn_g = (const float*)d_in[9];
  const float* bn_b = (const float*)d_in[10];
  const float* bnh_g = (const float*)d_in[11];
  const float* bnh_b = (const float*)d_in[12];
  const float* w1 = (const float*)d_in[13];
  const float* b1 = (const float*)d_in[14];
  const float* g1 = (const float*)d_in[15];
  const float* be1 = (const float*)d_in[16];
  const float* w2 = (const float*)d_in[17];
  const float* b2 = (const float*)d_in[18];
  const float* g2 = (const float*)d_in[19];
  const float* be2 = (const float*)d_in[20];
  const float* w3 = (const float*)d_in[21];
  const float* b3 = (const float*)d_in[22];
  const float* g3 = (const float*)d_in[23];
  const float* be3 = (const float*)d_in[24];
  const float* w4 = (const float*)d_in[25];
  const float* b4 = (const float*)d_in[26];
  const int* dstp = edge + EE;  // edge_index[1]

  char* ws = (char*)d_ws;
  int* deg = (int*)(ws);                                     // 64 KB
  int* cnt = (int*)(ws + 65536);                             // 256 B
  float* bufA = (float*)(ws + 131072);                       // 16 MiB
  float* bufB = (float*)(ws + 131072 + 16777216);            // 16 MiB
  float* pooled = (float*)(ws + 131072 + 2 * 16777216);      // 192 KB
  char* tail = ws + 131072 + 2 * 16777216 + 196608;
  float* m1 = (float*)(tail);                                // 64x512
  float* m1b = (float*)(tail + 131072);
  float* m2b = (float*)(tail + 262144);                      // 64x256
  float* m3b = (float*)(tail + 262144 + 65536);
  // z bf16 pairs live in bufA (h1 region, dead after conv2; h3 store skipped)
  ushort_t* zh = (ushort_t*)bufA;                            // 64*33408*2 = 4.28 MB
  ushort_t* zlp = zh + (size_t)64 * IN1;                     // 4.28 MB
  float* partial = bufB;  // S=128: 128*64*512*4 = 16,777,216 B == bufB exactly

  hipMemsetAsync(ws, 0, 131072, stream);            // deg + cnt
  hipMemsetAsync(pooled, 0, 196608, stream);        // pooled accumulators

  k_hist<<<528, 256, 0, stream>>>(dstp, batch, deg, cnt);

  // ---- 3 conv layers (MFMA bf16-pair), pooling fused; conv3 h-store skipped ----
  k_conv<<<dim3(2, 256), 256, 0, stream>>>(x, lin_dst_w, lin_dst_b, deg, bufA, pooled, 0);
  k_conv<<<dim3(2, 256), 256, 0, stream>>>(bufA, lin_dst_w + (size_t)FF * FF,
                                           lin_dst_b + FF, deg, bufB, pooled, FF);
  k_conv<<<dim3(2, 256), 256, 0, stream>>>(bufB, lin_dst_w + (size_t)2 * FF * FF,
                                           lin_dst_b + 2 * FF, deg, (float*)nullptr,
                                           pooled, 2 * FF);

  // ---- build z = [BN(xt) | BN(pooled/cnt)] as bf16 hi/lo pairs ----
  k_bn_front<<<259, 256, 0, stream>>>(x, bn_g, bn_b, pooled, cnt, bnh_g, bnh_b, zh, zlp);

  // ---- MLP ----
  k_w1<<<dim3(8, 128), 256, 0, stream>>>(zh, zlp, w1, partial);
  k_reduce<<<128, 256, 0, stream>>>(partial, b1, m1, 128, HIDN);
  k_bn_relu<<<HIDN, 64, 0, stream>>>(m1, g1, be1, m1b, HIDN);

  k_mlp_small<<<4, 512, 0, stream>>>(m1b, w2, b2, g2, be2, m2b, HIDN, 256);
  k_mlp_small<<<4, 512, 0, stream>>>(m2b, w3, b3, g3, be3, m3b, 256, 256);

  k_final<<<1, 256, 0, stream>>>(m3b, w4, b4, (float*)d_out);
}

// Round 7
// 201.569 us; speedup vs baseline: 2.1436x; 1.1212x over previous
//
#include <hip/hip_runtime.h>
#include <cstdint>

typedef __attribute__((ext_vector_type(8))) short short8;
typedef __attribute__((ext_vector_type(4))) float f32x4;
typedef unsigned short ushort_t;

static constexpr int NN = 16384, FF = 256, GG = 64, EE = 131072, LL = 3;
static constexpr int HIDN = 512, IU = 32640, IN1 = 33408;
#define EPSV 1e-5f

__device__ inline unsigned short bf16r(float v) {
  unsigned u = __float_as_uint(v);
  u += 0x7FFFu + ((u >> 16) & 1u);
  return (unsigned short)(u >> 16);
}

// ---------------- deg histogram + cnt (LDS histogram) ----------------
__global__ __launch_bounds__(256) void k_hist(const int* __restrict__ dst,
                                              const int* __restrict__ batch,
                                              int* __restrict__ deg, int* __restrict__ cnt) {
  __shared__ int hist[64];
  int bx = blockIdx.x, t = threadIdx.x;
  if (bx < 512) {
    int e = bx * 256 + t;
    atomicAdd(&deg[dst[e]], 1);
  } else {
    if (t < 64) hist[t] = 0;
    __syncthreads();
    int4 v = ((const int4*)batch)[(bx - 512) * 256 + t];
    int a[4] = {v.x, v.y, v.z, v.w};
    int cur = a[0], run = 1;
#pragma unroll
    for (int j = 1; j < 4; ++j) {
      if (a[j] == cur) run++;
      else { atomicAdd(&hist[cur], run); cur = a[j]; run = 1; }
    }
    atomicAdd(&hist[cur], run);
    __syncthreads();
    if (t < 64 && hist[t]) atomicAdd(&cnt[t], hist[t]);
  }
}

// ---------------- conv layer via MFMA bf16-pair: C = deg*(A@W+b), fused pooling ------
__global__ __launch_bounds__(256, 2) void k_conv(const float* __restrict__ A,
                                                 const float* __restrict__ W,
                                                 const float* __restrict__ bias,
                                                 const int* __restrict__ deg,
                                                 float* __restrict__ C,
                                                 float* __restrict__ pooled, int lofs) {
  __shared__ __align__(16) unsigned short Ah[64][72], Al[64][72];
  __shared__ __align__(16) unsigned short Bh[128][72], Bl[128][72];
  int n0 = blockIdx.x * 128, m0 = blockIdx.y * 64;
  int t = threadIdx.x;
  int w = t >> 6, l = t & 63;
  int wn = w * 32;
  int lr = l & 15, lg = l >> 4;
  f32x4 acc[4][2];
#pragma unroll
  for (int fm = 0; fm < 4; ++fm)
#pragma unroll
    for (int fn = 0; fn < 2; ++fn) acc[fm][fn] = (f32x4){0.f, 0.f, 0.f, 0.f};

  int am = t >> 2, aq = t & 3;
  int bkp = t & 3, bnf = (t >> 2) & 31, brr = t >> 7;

  for (int ks = 0; ks < 4; ++ks) {
    int k0 = ks * 64;
    if (ks) __syncthreads();
    {
      const float* ap = A + (size_t)(m0 + am) * FF + k0;
#pragma unroll
      for (int i = 0; i < 4; ++i) {
        int k = aq * 4 + i * 16;
        float4 v = *(const float4*)(ap + k);
        const float* vf = (const float*)&v;
        unsigned short h[4], lo[4];
#pragma unroll
        for (int j = 0; j < 4; ++j) {
          h[j] = bf16r(vf[j]);
          lo[j] = bf16r(vf[j] - __uint_as_float((unsigned)h[j] << 16));
        }
        *(uint2*)&Ah[am][k] = make_uint2((unsigned)h[0] | ((unsigned)h[1] << 16),
                                         (unsigned)h[2] | ((unsigned)h[3] << 16));
        *(uint2*)&Al[am][k] = make_uint2((unsigned)lo[0] | ((unsigned)lo[1] << 16),
                                         (unsigned)lo[2] | ((unsigned)lo[3] << 16));
      }
    }
#pragma unroll
    for (int r2 = 0; r2 < 4; ++r2) {
      int k = 2 * bkp + 8 * (brr * 4 + r2);
      const float* wp = W + (size_t)(k0 + k) * FF + n0 + bnf * 4;
      float4 va = *(const float4*)wp;
      float4 vb = *(const float4*)(wp + FF);
      const float* fa = (const float*)&va;
      const float* fb = (const float*)&vb;
#pragma unroll
      for (int j = 0; j < 4; ++j) {
        unsigned short ha = bf16r(fa[j]), hb = bf16r(fb[j]);
        unsigned short la = bf16r(fa[j] - __uint_as_float((unsigned)ha << 16));
        unsigned short lb = bf16r(fb[j] - __uint_as_float((unsigned)hb << 16));
        int n = bnf * 4 + j;
        *(unsigned*)&Bh[n][k] = (unsigned)ha | ((unsigned)hb << 16);
        *(unsigned*)&Bl[n][k] = (unsigned)la | ((unsigned)lb << 16);
      }
    }
    __syncthreads();
#pragma unroll
    for (int k2 = 0; k2 < 2; ++k2) {
      int kk = k2 * 32 + lg * 8;
      short8 afh[4], afl[4], bfh[2], bfl[2];
#pragma unroll
      for (int fm = 0; fm < 4; ++fm) {
        afh[fm] = *(const short8*)&Ah[fm * 16 + lr][kk];
        afl[fm] = *(const short8*)&Al[fm * 16 + lr][kk];
      }
#pragma unroll
      for (int fn = 0; fn < 2; ++fn) {
        bfh[fn] = *(const short8*)&Bh[wn + fn * 16 + lr][kk];
        bfl[fn] = *(const short8*)&Bl[wn + fn * 16 + lr][kk];
      }
#pragma unroll
      for (int fm = 0; fm < 4; ++fm)
#pragma unroll
        for (int fn = 0; fn < 2; ++fn) {
          acc[fm][fn] = __builtin_amdgcn_mfma_f32_16x16x32_bf16(afl[fm], bfh[fn], acc[fm][fn], 0, 0, 0);
          acc[fm][fn] = __builtin_amdgcn_mfma_f32_16x16x32_bf16(afh[fm], bfl[fn], acc[fm][fn], 0, 0, 0);
          acc[fm][fn] = __builtin_amdgcn_mfma_f32_16x16x32_bf16(afh[fm], bfh[fn], acc[fm][fn], 0, 0, 0);
        }
    }
  }
  float degf[4][4];
#pragma unroll
  for (int fm = 0; fm < 4; ++fm)
#pragma unroll
    for (int r = 0; r < 4; ++r)
      degf[fm][r] = (float)(deg[m0 + fm * 16 + lg * 4 + r] + 1);  // +1 self loop
  int g = m0 >> 8;
#pragma unroll
  for (int fn = 0; fn < 2; ++fn) {
    int col = n0 + wn + fn * 16 + lr;
    float bb = bias[col];
    float cs = 0.f;
#pragma unroll
    for (int fm = 0; fm < 4; ++fm) {
      const float* av = (const float*)&acc[fm][fn];
#pragma unroll
      for (int r = 0; r < 4; ++r) {
        int row = m0 + fm * 16 + lg * 4 + r;
        float v = (av[r] + bb) * degf[fm][r];
        if (C) C[(size_t)row * FF + col] = v;
        cs += v;
      }
    }
    cs += __shfl_xor(cs, 16);
    cs += __shfl_xor(cs, 32);
    if (lg == 0) atomicAdd(&pooled[(size_t)g * (FF * LL) + lofs + col], cs);
  }
}

// ---------------- front BN -> z emitted as bf16 hi/lo pair ----------------
__global__ __launch_bounds__(256) void k_bn_front(const float* __restrict__ x,
                                                  const float* __restrict__ bn_g,
                                                  const float* __restrict__ bn_b,
                                                  const float* __restrict__ pooled,
                                                  const int* __restrict__ cnt,
                                                  const float* __restrict__ bnh_g,
                                                  const float* __restrict__ bnh_b,
                                                  ushort_t* __restrict__ zh,
                                                  ushort_t* __restrict__ zl) {
  int bx = blockIdx.x;
  if (bx < 256) {
    int i = bx, j = threadIdx.x;
    if (j <= i) return;
    int p = i * 255 - (i * (i - 1)) / 2 + (j - i - 1);
    float vals[64];
    float s = 0.f, s2 = 0.f;
#pragma unroll
    for (int g = 0; g < 64; ++g) {
      float v = x[(size_t)(g * 256 + i) * FF + j];
      vals[g] = v;
      s += v;
      s2 += v * v;
    }
    float m = s * (1.f / 64.f);
    float var = s2 * (1.f / 64.f) - m * m;
    float rs = rsqrtf(var + EPSV) * bn_g[p];
    float bb = bn_b[p];
#pragma unroll
    for (int g = 0; g < 64; ++g) {
      float v = (vals[g] - m) * rs + bb;
      unsigned short h = bf16r(v);
      unsigned short lo = bf16r(v - __uint_as_float((unsigned)h << 16));
      zh[(size_t)g * IN1 + p] = h;
      zl[(size_t)g * IN1 + p] = lo;
    }
  } else {
    int q = (bx - 256) * 256 + threadIdx.x;
    if (q >= FF * LL) return;
    float vals[64];
    float s = 0.f, s2 = 0.f;
#pragma unroll
    for (int g = 0; g < 64; ++g) {
      float v = pooled[(size_t)g * (FF * LL) + q] / (float)cnt[g];
      vals[g] = v;
      s += v;
      s2 += v * v;
    }
    float m = s * (1.f / 64.f);
    float var = s2 * (1.f / 64.f) - m * m;
    float rs = rsqrtf(var + EPSV) * bnh_g[q];
    float bb = bnh_b[q];
#pragma unroll
    for (int g = 0; g < 64; ++g) {
      float v = (vals[g] - m) * rs + bb;
      unsigned short h = bf16r(v);
      unsigned short lo = bf16r(v - __uint_as_float((unsigned)h << 16));
      zh[(size_t)g * IN1 + IU + q] = h;
      zl[(size_t)g * IN1 + IU + q] = lo;
    }
  }
}

// ---------------- w1 GEMM via MFMA: partial[s][g][h], [64,33408]@[33408,512] ----------
__global__ __launch_bounds__(256, 2) void k_w1(const ushort_t* __restrict__ zh,
                                               const ushort_t* __restrict__ zl,
                                               const float* __restrict__ W,
                                               float* __restrict__ partial) {
  __shared__ __align__(16) unsigned short Zh[64][136], Zl[64][136];
  int nb = blockIdx.x, s = blockIdx.y;
  int t = threadIdx.x;
  int w = t >> 6, l = t & 63, lr = l & 15, lg = l >> 4;
  int ncol = nb * 64 + w * 16 + lr;
  f32x4 acc[4];
#pragma unroll
  for (int mt = 0; mt < 4; ++mt) acc[mt] = (f32x4){0.f, 0.f, 0.f, 0.f};

  for (int c = s; c < 261; c += 128) {  // 33408 = 261*128
    int p0 = c << 7;
#pragma unroll
    for (int it = 0; it < 4; ++it) {
      int idx = it * 256 + t;
      int g = idx >> 4, kq = idx & 15;
      *(uint4*)&Zh[g][kq * 8] = *(const uint4*)(zh + (size_t)g * IN1 + p0 + kq * 8);
      *(uint4*)&Zl[g][kq * 8] = *(const uint4*)(zl + (size_t)g * IN1 + p0 + kq * 8);
    }
    __syncthreads();
#pragma unroll
    for (int k2 = 0; k2 < 4; ++k2) {
      int kloc = k2 * 32 + lg * 8;
      size_t kg = (size_t)(p0 + kloc);
      float wv[8];
#pragma unroll
      for (int j = 0; j < 8; ++j) wv[j] = W[(kg + j) * HIDN + ncol];
      short8 bh, bl;
#pragma unroll
      for (int j = 0; j < 8; ++j) {
        unsigned u = __float_as_uint(wv[j]);
        unsigned hi = u & 0xFFFF0000u;
        float lo = wv[j] - __uint_as_float(hi);
        bh[j] = (short)(hi >> 16);
        bl[j] = (short)bf16r(lo);
      }
#pragma unroll
      for (int mt = 0; mt < 4; ++mt) {
        short8 ah = *(const short8*)&Zh[mt * 16 + lr][kloc];
        short8 al = *(const short8*)&Zl[mt * 16 + lr][kloc];
        acc[mt] = __builtin_amdgcn_mfma_f32_16x16x32_bf16(al, bh, acc[mt], 0, 0, 0);
        acc[mt] = __builtin_amdgcn_mfma_f32_16x16x32_bf16(ah, bl, acc[mt], 0, 0, 0);
        acc[mt] = __builtin_amdgcn_mfma_f32_16x16x32_bf16(ah, bh, acc[mt], 0, 0, 0);
      }
    }
    __syncthreads();
  }
#pragma unroll
  for (int mt = 0; mt < 4; ++mt) {
    const float* av = (const float*)&acc[mt];
#pragma unroll
    for (int r = 0; r < 4; ++r) {
      int g = mt * 16 + lg * 4 + r;
      partial[((size_t)s * 64 + g) * HIDN + ncol] = av[r];
    }
  }
}

// ---------------- reduce K-splits + bias ----------------
__global__ __launch_bounds__(256) void k_reduce(const float* __restrict__ partial,
                                                const float* __restrict__ bias,
                                                float* __restrict__ out, int S, int N) {
  int idx = blockIdx.x * 256 + threadIdx.x;
  if (idx >= 64 * N) return;
  int h = idx % N;
  float a = bias[h];
  for (int s = 0; s < S; ++s) a += partial[(size_t)s * 64 * N + idx];
  out[idx] = a;
}

// ---------------- column-wise BN over 64 rows + ReLU ----------------
__global__ __launch_bounds__(64) void k_bn_relu(const float* __restrict__ in,
                                                const float* __restrict__ gamma,
                                                const float* __restrict__ beta,
                                                float* __restrict__ out, int N) {
  int h = blockIdx.x;
  int g = threadIdx.x;
  float v = in[(size_t)g * N + h];
  float s = v, s2 = v * v;
#pragma unroll
  for (int o = 32; o > 0; o >>= 1) {
    s += __shfl_xor(s, o);
    s2 += __shfl_xor(s2, o);
  }
  float m = s * (1.f / 64.f);
  float var = s2 * (1.f / 64.f) - m * m;
  float r = (v - m) * rsqrtf(var + EPSV) * gamma[h] + beta[h];
  out[(size_t)g * N + h] = fmaxf(r, 0.f);
}

// ---------------- fused small MLP layer v2: out = relu(BN(Z@W + b)), M=64 -------------
// grid N/16 blocks x 256 thr; block owns 16 full output columns. W slice (K x 16,
// <=32 KB) staged ONCE in LDS coalesced; z in 128-k chunks; inner loop pure LDS+FMA.
// (round-6 version: 4 blocks + serial scalar global W loads -> 66 us of pure latency)
__global__ __launch_bounds__(256, 2) void k_mlp_small(const float* __restrict__ Z,
                                                      const float* __restrict__ W,
                                                      const float* __restrict__ bias,
                                                      const float* __restrict__ gamma,
                                                      const float* __restrict__ beta,
                                                      float* __restrict__ out, int K, int N) {
  __shared__ float Ws[512 * 16];       // K<=512 rows x 16 cols
  __shared__ float zl[64][132];
  __shared__ float sb1[16][17], sb2[16][17];
  int t = threadIdx.x;
  int h0 = blockIdx.x * 16;
  for (int idx = t; idx < K * 4; idx += 256) {
    int r = idx >> 2, q = idx & 3;
    *(float4*)&Ws[r * 16 + q * 4] = *(const float4*)(W + (size_t)r * N + h0 + q * 4);
  }
  int c = t & 15, gq = t >> 4;         // col c, row-group gq (4 rows each)
  float acc[4] = {};
  for (int ch = 0; ch < K; ch += 128) {
    for (int idx = t; idx < 64 * 32; idx += 256) {
      int g = idx >> 5, kq = idx & 31;
      *(float4*)&zl[g][kq * 4] = *(const float4*)(Z + (size_t)g * K + ch + kq * 4);
    }
    __syncthreads();
#pragma unroll 8
    for (int kk = 0; kk < 128; ++kk) {
      float w = Ws[(ch + kk) * 16 + c];
#pragma unroll
      for (int i = 0; i < 4; ++i) acc[i] = fmaf(zl[gq * 4 + i][kk], w, acc[i]);
    }
    __syncthreads();
  }
  float bb = bias[h0 + c];
  float s1 = 0.f, s2 = 0.f;
#pragma unroll
  for (int i = 0; i < 4; ++i) {
    acc[i] += bb;
    s1 += acc[i];
    s2 += acc[i] * acc[i];
  }
  sb1[gq][c] = s1;
  sb2[gq][c] = s2;
  __syncthreads();
  float S1 = 0.f, S2 = 0.f;
#pragma unroll
  for (int q = 0; q < 16; ++q) { S1 += sb1[q][c]; S2 += sb2[q][c]; }
  float m = S1 * (1.f / 64.f);
  float var = S2 * (1.f / 64.f) - m * m;
  float rs = rsqrtf(var + EPSV) * gamma[h0 + c];
  float be = beta[h0 + c];
#pragma unroll
  for (int i = 0; i < 4; ++i)
    out[(size_t)(gq * 4 + i) * N + h0 + c] = fmaxf((acc[i] - m) * rs + be, 0.f);
}

// ---------------- final: out = A @ w4 + b4, [64,256]@[256,2], wave-parallel ----------------
__global__ __launch_bounds__(256) void k_final(const float* __restrict__ A,
                                               const float* __restrict__ w4,
                                               const float* __restrict__ b4,
                                               float* __restrict__ out) {
  __shared__ float w4l[512];
  int t = threadIdx.x;
  w4l[t] = w4[t];
  w4l[256 + t] = w4[256 + t];
  __syncthreads();
  int w = t >> 6, l = t & 63;
  for (int g = w * 16; g < w * 16 + 16; ++g) {
    float4 av = *(const float4*)(A + (size_t)g * 256 + l * 4);
    float c0 = av.x * w4l[(l * 4 + 0) * 2] + av.y * w4l[(l * 4 + 1) * 2] +
               av.z * w4l[(l * 4 + 2) * 2] + av.w * w4l[(l * 4 + 3) * 2];
    float c1 = av.x * w4l[(l * 4 + 0) * 2 + 1] + av.y * w4l[(l * 4 + 1) * 2 + 1] +
               av.z * w4l[(l * 4 + 2) * 2 + 1] + av.w * w4l[(l * 4 + 3) * 2 + 1];
#pragma unroll
    for (int o = 32; o > 0; o >>= 1) {
      c0 += __shfl_xor(c0, o);
      c1 += __shfl_xor(c1, o);
    }
    if (l == 0) {
      out[g * 2 + 0] = c0 + b4[0];
      out[g * 2 + 1] = c1 + b4[1];
    }
  }
}

extern "C" void kernel_launch(void* const* d_in, const int* in_sizes, int n_in,
                              void* d_out, int out_size, void* d_ws, size_t ws_size,
                              hipStream_t stream) {
  const float* x = (const float*)d_in[0];
  const int* edge = (const int*)d_in[1];
  const int* batch = (const int*)d_in[2];
  // d_in[3],[4] lin_src_w/b: dead. d_in[7],[8] att_w/b: dead (softmax over singleton = 1).
  const float* lin_dst_w = (const float*)d_in[5];
  const float* lin_dst_b = (const float*)d_in[6];
  const float* bn_g = (const float*)d_in[9];
  const float* bn_b = (const float*)d_in[10];
  const float* bnh_g = (const float*)d_in[11];
  const float* bnh_b = (const float*)d_in[12];
  const float* w1 = (const float*)d_in[13];
  const float* b1 = (const float*)d_in[14];
  const float* g1 = (const float*)d_in[15];
  const float* be1 = (const float*)d_in[16];
  const float* w2 = (const float*)d_in[17];
  const float* b2 = (const float*)d_in[18];
  const float* g2 = (const float*)d_in[19];
  const float* be2 = (const float*)d_in[20];
  const float* w3 = (const float*)d_in[21];
  const float* b3 = (const float*)d_in[22];
  const float* g3 = (const float*)d_in[23];
  const float* be3 = (const float*)d_in[24];
  const float* w4 = (const float*)d_in[25];
  const float* b4 = (const float*)d_in[26];
  const int* dstp = edge + EE;  // edge_index[1]

  char* ws = (char*)d_ws;
  int* deg = (int*)(ws);                                     // 64 KB
  int* cnt = (int*)(ws + 65536);                             // 256 B
  float* bufA = (float*)(ws + 131072);                       // 16 MiB
  float* bufB = (float*)(ws + 131072 + 16777216);            // 16 MiB
  float* pooled = (float*)(ws + 131072 + 2 * 16777216);      // 192 KB
  char* tail = ws + 131072 + 2 * 16777216 + 196608;
  float* m1 = (float*)(tail);                                // 64x512
  float* m1b = (float*)(tail + 131072);
  float* m2b = (float*)(tail + 262144);                      // 64x256
  float* m3b = (float*)(tail + 262144 + 65536);
  // z bf16 pairs live in bufA (h1 region, dead after conv2; h3 store skipped)
  ushort_t* zh = (ushort_t*)bufA;                            // 64*33408*2 = 4.28 MB
  ushort_t* zlp = zh + (size_t)64 * IN1;                     // 4.28 MB
  float* partial = bufB;  // S=128: 128*64*512*4 = 16,777,216 B == bufB exactly

  hipMemsetAsync(ws, 0, 131072, stream);            // deg + cnt
  hipMemsetAsync(pooled, 0, 196608, stream);        // pooled accumulators

  k_hist<<<528, 256, 0, stream>>>(dstp, batch, deg, cnt);

  // ---- 3 conv layers (MFMA bf16-pair), pooling fused; conv3 h-store skipped ----
  k_conv<<<dim3(2, 256), 256, 0, stream>>>(x, lin_dst_w, lin_dst_b, deg, bufA, pooled, 0);
  k_conv<<<dim3(2, 256), 256, 0, stream>>>(bufA, lin_dst_w + (size_t)FF * FF,
                                           lin_dst_b + FF, deg, bufB, pooled, FF);
  k_conv<<<dim3(2, 256), 256, 0, stream>>>(bufB, lin_dst_w + (size_t)2 * FF * FF,
                                           lin_dst_b + 2 * FF, deg, (float*)nullptr,
                                           pooled, 2 * FF);

  // ---- build z = [BN(xt) | BN(pooled/cnt)] as bf16 hi/lo pairs ----
  k_bn_front<<<259, 256, 0, stream>>>(x, bn_g, bn_b, pooled, cnt, bnh_g, bnh_b, zh, zlp);

  // ---- MLP ----
  k_w1<<<dim3(8, 128), 256, 0, stream>>>(zh, zlp, w1, partial);
  k_reduce<<<128, 256, 0, stream>>>(partial, b1, m1, 128, HIDN);
  k_bn_relu<<<HIDN, 64, 0, stream>>>(m1, g1, be1, m1b, HIDN);

  k_mlp_small<<<16, 256, 0, stream>>>(m1b, w2, b2, g2, be2, m2b, HIDN, 256);
  k_mlp_small<<<16, 256, 0, stream>>>(m2b, w3, b3, g3, be3, m3b, 256, 256);

  k_final<<<1, 256, 0, stream>>>(m3b, w4, b4, (float*)d_out);
}